// Round 8
// baseline (1658.960 us; speedup 1.0000x reference)
//
#include <hip/hip_runtime.h>

#define B_ 2
#define S_ 2048
#define HD_ 2048
#define NH_ 16
#define DH_ 128
#define L_ 512
#define WINDOW_ 128
#define SINKS_ 16
#define KTOP_ 64
#define SCP 2064

typedef __attribute__((ext_vector_type(4))) float f32x4;
typedef __attribute__((ext_vector_type(8))) __bf16 bf16x8;

__device__ inline unsigned short f2bf(float f) {
  unsigned int u = __float_as_uint(f);
  unsigned int r = (u + 0x7FFFu + ((u >> 16) & 1u)) >> 16;
  return (unsigned short)r;
}
__device__ inline float bf2f(unsigned short u) {
  unsigned int x = ((unsigned int)u) << 16;
  return __uint_as_float(x);
}
__device__ inline float bfLO(unsigned int u) { return __uint_as_float(u << 16); }
__device__ inline float bfHI(unsigned int u) { return __uint_as_float(u & 0xffff0000u); }
__device__ inline unsigned int mono(float f) {
  unsigned int u = __float_as_uint(f);
  return (u & 0x80000000u) ? ~u : (u | 0x80000000u);
}
__device__ inline void gl16(const unsigned short* g, unsigned short* l) {
  __builtin_amdgcn_global_load_lds(
      (const __attribute__((address_space(1))) unsigned int*)g,
      (__attribute__((address_space(3))) unsigned int*)l, 16, 0, 0);
}

// ---------------- pack int32 forget mask -> bitmask (1 bit/elem) ----------------
__global__ __launch_bounds__(256) void pack_forget(const int* __restrict__ f,
                                                   unsigned int* __restrict__ p,
                                                   long long n) {
  long long i = (long long)blockIdx.x * 256 + threadIdx.x;
  int lane = threadIdx.x & 63;
  long long stride = (long long)gridDim.x * 256;
  for (; i < n; i += stride) {
    int v = f[i];
    unsigned long long m = __ballot(v != 0);
    if (lane == 0)  p[i >> 5] = (unsigned int)(m & 0xffffffffULL);
    if (lane == 32) p[i >> 5] = (unsigned int)(m >> 32);
  }
}

// ---------------- split f32 -> (hi, lo) bf16 (flat) ----------------
__global__ __launch_bounds__(256) void split_f32(const float* __restrict__ in,
                                                 unsigned short* __restrict__ hi,
                                                 unsigned short* __restrict__ lo,
                                                 int n) {
  int i = (blockIdx.x * 256 + threadIdx.x) * 4;
  int stride = gridDim.x * 256 * 4;
  for (; i < n; i += stride) {
    float4 v = *(const float4*)(in + i);
    ushort4 h, l;
    h.x = f2bf(v.x); l.x = f2bf(v.x - bf2f(h.x));
    h.y = f2bf(v.y); l.y = f2bf(v.y - bf2f(h.y));
    h.z = f2bf(v.z); l.z = f2bf(v.z - bf2f(h.z));
    h.w = f2bf(v.w); l.w = f2bf(v.w - bf2f(h.w));
    *(ushort4*)(hi + i) = h;
    *(ushort4*)(lo + i) = l;
  }
}

// ---------------- split + transpose: W[K,N] f32 -> WT[N,K] (hi,lo) bf16 ----------------
__global__ __launch_bounds__(256) void transpose_split(const float* __restrict__ W,
                                                       unsigned short* __restrict__ WTh,
                                                       unsigned short* __restrict__ WTl,
                                                       int K, int N) {
  __shared__ unsigned short th[32][33];
  __shared__ unsigned short tl[32][33];
  int n0 = blockIdx.x * 32, k0 = blockIdx.y * 32;
  int t = threadIdx.x;
  int cx = t & 31, ry = t >> 5;
#pragma unroll
  for (int it = 0; it < 4; ++it) {
    int kk = ry + it * 8;
    float v = W[(size_t)(k0 + kk) * N + n0 + cx];
    unsigned short h = f2bf(v);
    th[cx][kk] = h;
    tl[cx][kk] = f2bf(v - bf2f(h));
  }
  __syncthreads();
#pragma unroll
  for (int it = 0; it < 4; ++it) {
    int nn = ry + it * 8;
    WTh[(size_t)(n0 + nn) * K + k0 + cx] = th[nn][cx];
    WTl[(size_t)(n0 + nn) * K + k0 + cx] = tl[nn][cx];
  }
}

// ---------------- split-bf16 MFMA GEMM: C = (Ah+Al) * (Bh+Bl)^T ----------------
// 128x128 tile, 4 waves (2x2), BK=32, async global_load_lds staging (16B), LDP=40 pad.
#define LDP 40
#define ROWB (LDP * 2)          /* 80 bytes per LDS row */
#define BUFB (128 * ROWB)       /* 10240 bytes per buffer */
__global__ __launch_bounds__(256) void gemm_split(const unsigned short* __restrict__ Ah,
                                                  const unsigned short* __restrict__ Al,
                                                  const unsigned short* __restrict__ Bth,
                                                  const unsigned short* __restrict__ Btl,
                                                  float* __restrict__ Cf,
                                                  unsigned short* __restrict__ Chi,
                                                  unsigned short* __restrict__ Clo,
                                                  int M, int N, int K) {
  __shared__ unsigned short lAh[128][LDP];
  __shared__ unsigned short lAl[128][LDP];
  __shared__ unsigned short lBh[128][LDP];
  __shared__ unsigned short lBl[128][LDP];
  int t = threadIdx.x;
  int row0 = blockIdx.x * 128, col0 = blockIdx.y * 128;
  int w = t >> 6, lane = t & 63;
  int wm = w >> 1, wn = w & 1;
  int lr = lane & 15, g = lane >> 4;

  f32x4 acc[4][4] = {};

  for (int kt = 0; kt < K; kt += 32) {
#pragma unroll
    for (int kissue = 0; kissue < 3; ++kissue) {
      int chunk = kissue * 4 + w;
      int Lb = chunk * 1024;
      if (Lb < BUFB) {
        int L = Lb + lane * 16;
        int rr = L / ROWB;
        int cb = L - rr * ROWB;
        int kk = (cb < 64) ? (cb >> 1) : 0;
        size_t offA = (size_t)(row0 + rr) * K + kt + kk;
        size_t offB = (size_t)(col0 + rr) * K + kt + kk;
        gl16(Ah + offA, &lAh[0][0] + Lb / 2);
        gl16(Al + offA, &lAl[0][0] + Lb / 2);
        gl16(Bth + offB, &lBh[0][0] + Lb / 2);
        gl16(Btl + offB, &lBl[0][0] + Lb / 2);
      }
    }
    __syncthreads();
    bf16x8 afh[4], afl[4], bgh[4], bgl[4];
#pragma unroll
    for (int m = 0; m < 4; ++m) {
      afh[m] = *(const bf16x8*)&lAh[wm * 64 + m * 16 + lr][g * 8];
      afl[m] = *(const bf16x8*)&lAl[wm * 64 + m * 16 + lr][g * 8];
    }
#pragma unroll
    for (int n = 0; n < 4; ++n) {
      bgh[n] = *(const bf16x8*)&lBh[wn * 64 + n * 16 + lr][g * 8];
      bgl[n] = *(const bf16x8*)&lBl[wn * 64 + n * 16 + lr][g * 8];
    }
#pragma unroll
    for (int m = 0; m < 4; ++m)
#pragma unroll
      for (int n = 0; n < 4; ++n) {
        acc[m][n] = __builtin_amdgcn_mfma_f32_16x16x32_bf16(afh[m], bgh[n], acc[m][n], 0, 0, 0);
        acc[m][n] = __builtin_amdgcn_mfma_f32_16x16x32_bf16(afh[m], bgl[n], acc[m][n], 0, 0, 0);
        acc[m][n] = __builtin_amdgcn_mfma_f32_16x16x32_bf16(afl[m], bgh[n], acc[m][n], 0, 0, 0);
      }
    __syncthreads();
  }

#pragma unroll
  for (int m = 0; m < 4; ++m)
#pragma unroll
    for (int n = 0; n < 4; ++n)
#pragma unroll
      for (int r2 = 0; r2 < 4; ++r2) {
        int row = row0 + wm * 64 + m * 16 + g * 4 + r2;
        int col = col0 + wn * 64 + n * 16 + lr;
        float val = acc[m][n][r2];
        if (Cf) {
          Cf[(size_t)row * N + col] = val;
        } else {
          unsigned short hh = f2bf(val);
          Chi[(size_t)row * N + col] = hh;
          if (Clo) Clo[(size_t)row * N + col] = f2bf(val - bf2f(hh));
        }
      }
}

// ---------------- attn select: scores + exact top-k + softmax lists ----------------
// One block = (b, h, 16 query rows). 1024 threads = 16 waves; one row per wave.
__global__ __launch_bounds__(1024, 4) void attn_select(const unsigned short* __restrict__ qh,
                                                       const unsigned short* __restrict__ ql,
                                                       const unsigned short* __restrict__ kh,
                                                       const unsigned short* __restrict__ kl,
                                                       const unsigned int* __restrict__ pf,
                                                       unsigned short* __restrict__ gidx,
                                                       float* __restrict__ gw,
                                                       int* __restrict__ gcnt,
                                                       float* __restrict__ ginv) {
  __shared__ float sc[16][SCP];
  __shared__ unsigned int hist[16][128];   // 256 buckets packed as 2x u16 per word
  __shared__ unsigned short lidx[16][224];

  int bid = blockIdx.x;
  int tile = bid & 127;
  int h = (bid >> 7) & 15;
  int b = bid >> 11;
  int i0 = tile * 16;
  int t = threadIdx.x;
  int w = t >> 6, lane = t & 63;
  int lr = lane & 15, g = lane >> 4;
  const float scale = 0.08838834764831845f;

  // ---- Phase A: scores via split MFMA; all 16 C-rows are live query rows ----
  int jmaxT = i0 + 15;
  int qr = i0 + lr;
  size_t qbase = ((size_t)(b * S_ + qr)) * HD_ + h * DH_;
  bf16x8 aqh[4], aql[4];
#pragma unroll
  for (int ks = 0; ks < 4; ++ks) {
    aqh[ks] = *(const bf16x8*)(qh + qbase + ks * 32 + g * 8);
    aql[ks] = *(const bf16x8*)(ql + qbase + ks * 32 + g * 8);
  }

  for (int kblk = w; kblk * 16 <= jmaxT; kblk += 16) {
    int j0 = kblk * 16;
    int jj = j0 + lr; if (jj > jmaxT) jj = jmaxT;
    size_t kbase = ((size_t)(b * S_ + jj)) * HD_ + h * DH_;
    f32x4 acc = {0.f, 0.f, 0.f, 0.f};
#pragma unroll
    for (int ks = 0; ks < 4; ++ks) {
      bf16x8 bkh = *(const bf16x8*)(kh + kbase + ks * 32 + g * 8);
      bf16x8 bkl = *(const bf16x8*)(kl + kbase + ks * 32 + g * 8);
      acc = __builtin_amdgcn_mfma_f32_16x16x32_bf16(aqh[ks], bkh, acc, 0, 0, 0);
      acc = __builtin_amdgcn_mfma_f32_16x16x32_bf16(aqh[ks], bkl, acc, 0, 0, 0);
      acc = __builtin_amdgcn_mfma_f32_16x16x32_bf16(aql[ks], bkh, acc, 0, 0, 0);
    }
#pragma unroll
    for (int r2 = 0; r2 < 4; ++r2) {
      int rr = g * 4 + r2;
      int col = j0 + lr;
      if (col <= jmaxT) sc[rr][col] = acc[r2] * scale;
    }
  }
  __syncthreads();

  // ---- Phase B: wave-private row select; score row in registers ----
  int r = w;
  int i = i0 + r;
  size_t row = ((size_t)(b * NH_ + h)) * S_ + i;
  int lo = SINKS_, hi = i - WINDOW_;
  int C = hi - lo + 1;
  int mode = (C <= 0) ? 0 : (C <= KTOP_ ? 1 : 2);
  unsigned int T = 0; int neq = 0;

  unsigned int fw = pf[row * (S_ / 32) + lane];

  float rv[32];
#pragma unroll
  for (int c = 0; c < 32; ++c) rv[c] = sc[r][c * 64 + lane];

  if (mode == 2) {
    unsigned int need = KTOP_;
    unsigned int prefix = 0;
    unsigned int chmask = 0xffffffffu;
    for (int pass = 0; pass < 4; ++pass) {
      int shift = 24 - pass * 8;
      hist[w][lane] = 0;
      hist[w][lane + 64] = 0;
#pragma unroll
      for (int c = 0; c < 32; ++c) {
        int jA = c * 64;
        if (jA <= hi && ((chmask >> c) & 1)) {
          int j = jA + lane;
          bool cand = (j >= lo) && (j <= hi);
          unsigned int key = mono(rv[c]);
          bool match = cand && (pass == 0 || ((key >> (shift + 8)) == prefix));
          if (match) {
            unsigned int bkt = (key >> shift) & 255u;
            atomicAdd(&hist[w][bkt >> 1], 1u << ((bkt & 1u) * 16));
          }
        }
      }
      unsigned int w0 = hist[w][lane * 2], w1 = hist[w][lane * 2 + 1];
      unsigned int s0 = (w0 & 0xffffu) + (w0 >> 16) + (w1 & 0xffffu) + (w1 >> 16);
      unsigned int suf = s0;
#pragma unroll
      for (int off = 1; off < 64; off <<= 1) {
        unsigned int vv = __shfl_down(suf, off);
        if (lane + off < 64) suf += vv;
      }
      unsigned int sufn = __shfl_down(suf, 1);
      if (lane == 63) sufn = 0;
      bool pl = (suf >= need) && (sufn < need);
      unsigned long long bal = __ballot(pl);
      int gg = __ffsll(bal) - 1;
      unsigned int basec = __shfl(sufn, gg);
      unsigned int cum = basec; int dstar = 4 * gg;
#pragma unroll
      for (int dd = 3; dd >= 0; --dd) {
        int d = 4 * gg + dd;
        unsigned int hd = (hist[w][d >> 1] >> ((d & 1) * 16)) & 0xffffu;
        cum += hd;
        if (cum >= need) { dstar = d; break; }
      }
      unsigned int hstar = (hist[w][dstar >> 1] >> ((dstar & 1) * 16)) & 0xffffu;
      unsigned int cnt_gt = cum - hstar;
      need -= cnt_gt;
      unsigned int newpref = (prefix << 8) | (unsigned int)dstar;
      if (pass < 3) {
        unsigned int nm = 0;
#pragma unroll
        for (int c = 0; c < 32; ++c) {
          int jA = c * 64;
          if (jA <= hi && ((chmask >> c) & 1)) {
            int j = jA + lane;
            bool cand = (j >= lo) && (j <= hi);
            unsigned int key = mono(rv[c]);
            bool m1 = cand && ((key >> shift) == newpref);
            if (__ballot(m1)) nm |= (1u << c);
          }
        }
        chmask = nm;
      }
      prefix = newpref;
    }
    T = prefix; neq = (int)need;
  }

  // fused marking + compaction + vmax (ascending tie order preserved)
  float vmax = -3.4e38f;
  int neq_run = neq;
  int cnt = 0;
#pragma unroll
  for (int c = 0; c < 32; ++c) {
    int jA = c * 64;
    if (jA <= i) {
      int j = jA + lane;
      unsigned int wv = __shfl(fw, (jA >> 5) + (lane >> 5));  // uniform-active shfl
      bool fbit = (wv >> (j & 31)) & 1;
      bool valid = j <= i;
      float s = rv[c];
      bool isbase = valid && ((j < SINKS_) || ((i - j) < WINDOW_));
      bool iscand = valid && !isbase;
      bool sel = false, iseq = false;
      if (iscand) {
        if (mode == 1) sel = true;
        else if (mode == 2) {
          unsigned int key = mono(s);
          sel = key > T;
          iseq = (key == T);
        }
      }
      unsigned long long em = __ballot(iseq);
      if (iseq) {
        int rk = __popcll(em & ((1ull << lane) - 1ull));
        if (rk < neq_run) sel = true;
      }
      int taken = __popcll(em);
      neq_run -= (taken < neq_run) ? taken : neq_run;
      if (sel && fbit) sel = false;
      bool allowed = isbase || sel;
      if (allowed) vmax = fmaxf(vmax, s);
      unsigned long long am = __ballot(allowed);
      if (allowed) {
        int pos = cnt + __popcll(am & ((1ull << lane) - 1ull));
        lidx[r][pos] = (unsigned short)j;
      }
      cnt += __popcll(am);
    }
  }
#pragma unroll
  for (int off = 32; off >= 1; off >>= 1) vmax = fmaxf(vmax, __shfl_xor(vmax, off));

  // weights over the compact list -> global (unnormalized)
  float sum = 0.f;
  size_t lbase = row * 224;
  for (int p = lane; p < cnt; p += 64) {
    int j = lidx[r][p];
    float wgt = __expf(sc[r][j] - vmax);
    gw[lbase + p] = wgt;
    gidx[lbase + p] = (unsigned short)j;
    sum += wgt;
  }
#pragma unroll
  for (int off = 32; off >= 1; off >>= 1) sum += __shfl_xor(sum, off);
  if (lane == 0) { gcnt[row] = cnt; ginv[row] = 1.0f / sum; }
}

// ---------------- attn PV: gather V by compact lists, zero LDS ----------------
__global__ __launch_bounds__(256) void attn_pv(const unsigned short* __restrict__ vbf,
                                               const unsigned short* __restrict__ gidx,
                                               const float* __restrict__ gw,
                                               const int* __restrict__ gcnt,
                                               const float* __restrict__ ginv,
                                               unsigned short* __restrict__ oh,
                                               unsigned short* __restrict__ ol) {
  int t = threadIdx.x;
  int w = t >> 6, lane = t & 63;
  size_t row = (size_t)blockIdx.x * 4 + w;
  int b = (int)(row >> 15);
  int h = (int)((row >> 11) & 15);
  int i = (int)(row & 2047);

  int cnt = gcnt[row];
  float inv = ginv[row];
  size_t lbase = row * 224;

  int half = lane >> 5;
  int q = lane & 31;
  int d0 = q * 4;
  int pmid = (cnt + 1) >> 1;
  int p0 = half ? pmid : 0;
  int p1 = half ? cnt : pmid;
  size_t vbase = ((size_t)b * S_) * HD_ + h * DH_ + d0;

  float a0 = 0.f, a1 = 0.f, a2 = 0.f, a3 = 0.f;
  int p = p0;
  for (; p + 8 <= p1; p += 8) {
    int jj[8]; float wj[8]; uint2 vj[8];
#pragma unroll
    for (int u = 0; u < 8; ++u) {
      jj[u] = gidx[lbase + p + u];
      wj[u] = gw[lbase + p + u];
    }
#pragma unroll
    for (int u = 0; u < 8; ++u)
      vj[u] = *(const uint2*)(vbf + vbase + (size_t)jj[u] * HD_);
#pragma unroll
    for (int u = 0; u < 8; ++u) {
      a0 += wj[u] * bfLO(vj[u].x);
      a1 += wj[u] * bfHI(vj[u].x);
      a2 += wj[u] * bfLO(vj[u].y);
      a3 += wj[u] * bfHI(vj[u].y);
    }
  }
  for (; p < p1; ++p) {
    int jj = gidx[lbase + p];
    float wj = gw[lbase + p];
    uint2 vj = *(const uint2*)(vbf + vbase + (size_t)jj * HD_);
    a0 += wj * bfLO(vj.x); a1 += wj * bfHI(vj.x);
    a2 += wj * bfLO(vj.y); a3 += wj * bfHI(vj.y);
  }
  a0 += __shfl_xor(a0, 32);
  a1 += __shfl_xor(a1, 32);
  a2 += __shfl_xor(a2, 32);
  a3 += __shfl_xor(a3, 32);
  if (half == 0) {
    float v0 = a0 * inv, v1 = a1 * inv, v2 = a2 * inv, v3 = a3 * inv;
    ushort4 ho, lo4;
    ho.x = f2bf(v0); lo4.x = f2bf(v0 - bf2f(ho.x));
    ho.y = f2bf(v1); lo4.y = f2bf(v1 - bf2f(ho.y));
    ho.z = f2bf(v2); lo4.z = f2bf(v2 - bf2f(ho.z));
    ho.w = f2bf(v3); lo4.w = f2bf(v3 - bf2f(ho.w));
    size_t oidx = ((size_t)(b * S_ + i)) * HD_ + h * DH_ + d0;
    *(ushort4*)(oh + oidx) = ho;
    *(ushort4*)(ol + oidx) = lo4;
  }
}

extern "C" void kernel_launch(void* const* d_in, const int* in_sizes, int n_in,
                              void* d_out, int out_size, void* d_ws, size_t ws_size,
                              hipStream_t stream) {
  (void)in_sizes; (void)n_in; (void)out_size; (void)ws_size;
  const float* x  = (const float*)d_in[0];
  const float* Wq = (const float*)d_in[1];
  const float* Wc = (const float*)d_in[2];
  const float* Wk = (const float*)d_in[3];
  const float* Wv = (const float*)d_in[4];
  const float* Wo = (const float*)d_in[5];
  const int* forget = (const int*)d_in[6];  // bool widened to int32 (verified r3)

  char* ws = (char*)d_ws;
  size_t off = 0;
  auto alloc = [&](size_t bytes) { char* p = ws + off; off += (bytes + 255) & ~(size_t)255; return p; };

  unsigned short* x_hi = (unsigned short*)alloc((size_t)4096 * 2048 * 2);  // reused as o_hi
  unsigned short* x_lo = (unsigned short*)alloc((size_t)4096 * 2048 * 2);  // reused as o_lo
  unsigned short* WqTh = (unsigned short*)alloc((size_t)2048 * 2048 * 2);
  unsigned short* WqTl = (unsigned short*)alloc((size_t)2048 * 2048 * 2);
  unsigned short* WcTh = (unsigned short*)alloc((size_t)512 * 2048 * 2);
  unsigned short* WcTl = (unsigned short*)alloc((size_t)512 * 2048 * 2);
  unsigned short* WkTh = (unsigned short*)alloc((size_t)2048 * 512 * 2);
  unsigned short* WkTl = (unsigned short*)alloc((size_t)2048 * 512 * 2);
  unsigned short* WvTh = (unsigned short*)alloc((size_t)2048 * 512 * 2);
  unsigned short* WvTl = (unsigned short*)alloc((size_t)2048 * 512 * 2);
  unsigned short* WoTh = (unsigned short*)alloc((size_t)2048 * 2048 * 2);
  unsigned short* WoTl = (unsigned short*)alloc((size_t)2048 * 2048 * 2);
  unsigned short* q_hi = (unsigned short*)alloc((size_t)4096 * 2048 * 2);
  unsigned short* q_lo = (unsigned short*)alloc((size_t)4096 * 2048 * 2);
  unsigned short* c_hi = (unsigned short*)alloc((size_t)4096 * 512 * 2);
  unsigned short* c_lo = (unsigned short*)alloc((size_t)4096 * 512 * 2);
  unsigned short* k_hi = (unsigned short*)alloc((size_t)4096 * 2048 * 2);
  unsigned short* k_lo = (unsigned short*)alloc((size_t)4096 * 2048 * 2);
  unsigned short* v_bf = (unsigned short*)alloc((size_t)4096 * 2048 * 2);
  unsigned int*  fpack = (unsigned int*)alloc((size_t)(134217728 / 8));
  unsigned short* gidx = (unsigned short*)alloc((size_t)65536 * 224 * 2);
  float*          gwv  = (float*)alloc((size_t)65536 * 224 * 4);
  int*            gcnt = (int*)alloc((size_t)65536 * 4);
  float*          ginv = (float*)alloc((size_t)65536 * 4);

  unsigned short* o_hi = x_hi;
  unsigned short* o_lo = x_lo;

  pack_forget<<<8192, 256, 0, stream>>>(forget, fpack, 134217728LL);

  split_f32<<<2048, 256, 0, stream>>>(x, x_hi, x_lo, 4096 * 2048);
  transpose_split<<<dim3(64, 64), 256, 0, stream>>>(Wq, WqTh, WqTl, 2048, 2048);
  transpose_split<<<dim3(16, 64), 256, 0, stream>>>(Wc, WcTh, WcTl, 2048, 512);
  transpose_split<<<dim3(64, 16), 256, 0, stream>>>(Wk, WkTh, WkTl, 512, 2048);
  transpose_split<<<dim3(64, 16), 256, 0, stream>>>(Wv, WvTh, WvTl, 512, 2048);
  transpose_split<<<dim3(64, 64), 256, 0, stream>>>(Wo, WoTh, WoTl, 2048, 2048);

  gemm_split<<<dim3(32, 4),  256, 0, stream>>>(x_hi, x_lo, WcTh, WcTl, nullptr, c_hi, c_lo, 4096, 512, 2048);
  gemm_split<<<dim3(32, 16), 256, 0, stream>>>(x_hi, x_lo, WqTh, WqTl, nullptr, q_hi, q_lo, 4096, 2048, 2048);
  gemm_split<<<dim3(32, 16), 256, 0, stream>>>(c_hi, c_lo, WkTh, WkTl, nullptr, k_hi, k_lo, 4096, 2048, 512);
  gemm_split<<<dim3(32, 16), 256, 0, stream>>>(c_hi, c_lo, WvTh, WvTl, nullptr, v_bf, nullptr, 4096, 2048, 512);

  attn_select<<<4096, 1024, 0, stream>>>(q_hi, q_lo, k_hi, k_lo, fpack, gidx, gwv, gcnt, ginv);
  attn_pv<<<16384, 256, 0, stream>>>(v_bf, gidx, gwv, gcnt, ginv, o_hi, o_lo);

  gemm_split<<<dim3(32, 16), 256, 0, stream>>>(o_hi, o_lo, WoTh, WoTl, (float*)d_out, nullptr, nullptr, 4096, 2048, 2048);
}

// Round 9
// 1520.443 us; speedup vs baseline: 1.0911x; 1.0911x over previous
//
#include <hip/hip_runtime.h>

#define B_ 2
#define S_ 2048
#define HD_ 2048
#define NH_ 16
#define DH_ 128
#define L_ 512
#define WINDOW_ 128
#define SINKS_ 16
#define KTOP_ 64

typedef __attribute__((ext_vector_type(4))) float f32x4;
typedef __attribute__((ext_vector_type(8))) __bf16 bf16x8;

__device__ inline unsigned short f2bf(float f) {
  unsigned int u = __float_as_uint(f);
  unsigned int r = (u + 0x7FFFu + ((u >> 16) & 1u)) >> 16;
  return (unsigned short)r;
}
__device__ inline float bf2f(unsigned short u) {
  unsigned int x = ((unsigned int)u) << 16;
  return __uint_as_float(x);
}
__device__ inline float bfLO(unsigned int u) { return __uint_as_float(u << 16); }
__device__ inline float bfHI(unsigned int u) { return __uint_as_float(u & 0xffff0000u); }
__device__ inline unsigned int mono(float f) {
  unsigned int u = __float_as_uint(f);
  return (u & 0x80000000u) ? ~u : (u | 0x80000000u);
}

// ---------------- pack int32 forget mask -> bitmask (1 bit/elem) ----------------
__global__ __launch_bounds__(256) void pack_forget(const int* __restrict__ f,
                                                   unsigned int* __restrict__ p,
                                                   long long n) {
  long long i = (long long)blockIdx.x * 256 + threadIdx.x;
  int lane = threadIdx.x & 63;
  long long stride = (long long)gridDim.x * 256;
  for (; i < n; i += stride) {
    int v = f[i];
    unsigned long long m = __ballot(v != 0);
    if (lane == 0)  p[i >> 5] = (unsigned int)(m & 0xffffffffULL);
    if (lane == 32) p[i >> 5] = (unsigned int)(m >> 32);
  }
}

// ---------------- split f32 -> (hi, lo) bf16 (flat) ----------------
__global__ __launch_bounds__(256) void split_f32(const float* __restrict__ in,
                                                 unsigned short* __restrict__ hi,
                                                 unsigned short* __restrict__ lo,
                                                 int n) {
  int i = (blockIdx.x * 256 + threadIdx.x) * 4;
  int stride = gridDim.x * 256 * 4;
  for (; i < n; i += stride) {
    float4 v = *(const float4*)(in + i);
    ushort4 h, l;
    h.x = f2bf(v.x); l.x = f2bf(v.x - bf2f(h.x));
    h.y = f2bf(v.y); l.y = f2bf(v.y - bf2f(h.y));
    h.z = f2bf(v.z); l.z = f2bf(v.z - bf2f(h.z));
    h.w = f2bf(v.w); l.w = f2bf(v.w - bf2f(h.w));
    *(ushort4*)(hi + i) = h;
    *(ushort4*)(lo + i) = l;
  }
}

// ---------------- split + transpose: W[K,N] f32 -> WT[N,K] (hi,lo) bf16 ----------------
__global__ __launch_bounds__(256) void transpose_split(const float* __restrict__ W,
                                                       unsigned short* __restrict__ WTh,
                                                       unsigned short* __restrict__ WTl,
                                                       int K, int N) {
  __shared__ unsigned short th[32][33];
  __shared__ unsigned short tl[32][33];
  int n0 = blockIdx.x * 32, k0 = blockIdx.y * 32;
  int t = threadIdx.x;
  int cx = t & 31, ry = t >> 5;
#pragma unroll
  for (int it = 0; it < 4; ++it) {
    int kk = ry + it * 8;
    float v = W[(size_t)(k0 + kk) * N + n0 + cx];
    unsigned short h = f2bf(v);
    th[cx][kk] = h;
    tl[cx][kk] = f2bf(v - bf2f(h));
  }
  __syncthreads();
#pragma unroll
  for (int it = 0; it < 4; ++it) {
    int nn = ry + it * 8;
    WTh[(size_t)(n0 + nn) * K + k0 + cx] = th[nn][cx];
    WTl[(size_t)(n0 + nn) * K + k0 + cx] = tl[nn][cx];
  }
}

// ---------------- split-bf16 MFMA GEMM: C = (Ah+Al) * (Bh+Bl)^T (r6 staging) ----------------
#define LDP 40
__global__ __launch_bounds__(256) void gemm_split(const unsigned short* __restrict__ Ah,
                                                  const unsigned short* __restrict__ Al,
                                                  const unsigned short* __restrict__ Bth,
                                                  const unsigned short* __restrict__ Btl,
                                                  float* __restrict__ Cf,
                                                  unsigned short* __restrict__ Chi,
                                                  unsigned short* __restrict__ Clo,
                                                  int M, int N, int K) {
  __shared__ unsigned short lAh[128][LDP];
  __shared__ unsigned short lAl[128][LDP];
  __shared__ unsigned short lBh[128][LDP];
  __shared__ unsigned short lBl[128][LDP];
  int t = threadIdx.x;
  int row0 = blockIdx.x * 128, col0 = blockIdx.y * 128;
  int w = t >> 6, lane = t & 63;
  int wm = w >> 1, wn = w & 1;
  int lr = lane & 15, g = lane >> 4;

  f32x4 acc[4][4] = {};

  for (int kt = 0; kt < K; kt += 32) {
#pragma unroll
    for (int cc = 0; cc < 2; ++cc) {
      int c = t * 2 + cc;
      int ar = c >> 2, kc = (c & 3) * 8;
      size_t offA = (size_t)(row0 + ar) * K + kt + kc;
      size_t offB = (size_t)(col0 + ar) * K + kt + kc;
      *(int4*)&lAh[ar][kc] = *(const int4*)(Ah + offA);
      *(int4*)&lAl[ar][kc] = *(const int4*)(Al + offA);
      *(int4*)&lBh[ar][kc] = *(const int4*)(Bth + offB);
      *(int4*)&lBl[ar][kc] = *(const int4*)(Btl + offB);
    }
    __syncthreads();
    bf16x8 afh[4], afl[4], bgh[4], bgl[4];
#pragma unroll
    for (int m = 0; m < 4; ++m) {
      afh[m] = *(const bf16x8*)&lAh[wm * 64 + m * 16 + lr][g * 8];
      afl[m] = *(const bf16x8*)&lAl[wm * 64 + m * 16 + lr][g * 8];
    }
#pragma unroll
    for (int n = 0; n < 4; ++n) {
      bgh[n] = *(const bf16x8*)&lBh[wn * 64 + n * 16 + lr][g * 8];
      bgl[n] = *(const bf16x8*)&lBl[wn * 64 + n * 16 + lr][g * 8];
    }
#pragma unroll
    for (int m = 0; m < 4; ++m)
#pragma unroll
      for (int n = 0; n < 4; ++n) {
        acc[m][n] = __builtin_amdgcn_mfma_f32_16x16x32_bf16(afh[m], bgh[n], acc[m][n], 0, 0, 0);
        acc[m][n] = __builtin_amdgcn_mfma_f32_16x16x32_bf16(afh[m], bgl[n], acc[m][n], 0, 0, 0);
        acc[m][n] = __builtin_amdgcn_mfma_f32_16x16x32_bf16(afl[m], bgh[n], acc[m][n], 0, 0, 0);
      }
    __syncthreads();
  }

#pragma unroll
  for (int m = 0; m < 4; ++m)
#pragma unroll
    for (int n = 0; n < 4; ++n)
#pragma unroll
      for (int r2 = 0; r2 < 4; ++r2) {
        int row = row0 + wm * 64 + m * 16 + g * 4 + r2;
        int col = col0 + wn * 64 + n * 16 + lr;
        float val = acc[m][n][r2];
        if (Cf) {
          Cf[(size_t)row * N + col] = val;
        } else {
          unsigned short hh = f2bf(val);
          Chi[(size_t)row * N + col] = hh;
          if (Clo) Clo[(size_t)row * N + col] = f2bf(val - bf2f(hh));
        }
      }
}

// ---------------- attn scores: QK^T (split) for one (b, h-half) slice -> global f32 ----------------
// grid (128 tiles, 8 heads), 256 threads = 4 waves striding key tiles.
__global__ __launch_bounds__(256) void attn_scores(const unsigned short* __restrict__ qh,
                                                   const unsigned short* __restrict__ ql,
                                                   const unsigned short* __restrict__ kh,
                                                   const unsigned short* __restrict__ kl,
                                                   int b, int h0,
                                                   float* __restrict__ scb) {
  int tile = blockIdx.x;
  int h8 = blockIdx.y;
  int h = h0 + h8;
  int i0 = tile * 16;
  int t = threadIdx.x;
  int w = t >> 6, lane = t & 63;
  int lr = lane & 15, g = lane >> 4;
  const float scale = 0.08838834764831845f;
  int jmaxT = i0 + 15;

  size_t qbase = ((size_t)(b * S_ + i0 + lr)) * HD_ + h * DH_;
  bf16x8 aqh[4], aql[4];
#pragma unroll
  for (int ks = 0; ks < 4; ++ks) {
    aqh[ks] = *(const bf16x8*)(qh + qbase + ks * 32 + g * 8);
    aql[ks] = *(const bf16x8*)(ql + qbase + ks * 32 + g * 8);
  }

  for (int kblk = w; kblk * 16 <= jmaxT; kblk += 4) {
    int j0 = kblk * 16;
    int jj = j0 + lr; if (jj > jmaxT) jj = jmaxT;
    size_t kbase = ((size_t)(b * S_ + jj)) * HD_ + h * DH_;
    f32x4 acc = {0.f, 0.f, 0.f, 0.f};
#pragma unroll
    for (int ks = 0; ks < 4; ++ks) {
      bf16x8 bkh = *(const bf16x8*)(kh + kbase + ks * 32 + g * 8);
      bf16x8 bkl = *(const bf16x8*)(kl + kbase + ks * 32 + g * 8);
      acc = __builtin_amdgcn_mfma_f32_16x16x32_bf16(aqh[ks], bkh, acc, 0, 0, 0);
      acc = __builtin_amdgcn_mfma_f32_16x16x32_bf16(aqh[ks], bkl, acc, 0, 0, 0);
      acc = __builtin_amdgcn_mfma_f32_16x16x32_bf16(aql[ks], bkh, acc, 0, 0, 0);
    }
#pragma unroll
    for (int r2 = 0; r2 < 4; ++r2) {
      int rr = g * 4 + r2;
      int col = j0 + lr;
      if (col <= jmaxT)
        scb[((size_t)(h8 * S_ + i0 + rr)) * S_ + col] = acc[r2] * scale;
    }
  }
}

// ---------------- attn select+PV: one wave per row, scores from global ----------------
// block 256 = 4 waves; ~7.4 KB LDS. 2-pass 16-bit radix, exact-order tie fill, forget, PV.
__global__ __launch_bounds__(256, 6) void attn_select2(const float* __restrict__ scb,
                                                       const unsigned short* __restrict__ vbf,
                                                       const unsigned int* __restrict__ pf,
                                                       int b, int h0,
                                                       unsigned short* __restrict__ oh,
                                                       unsigned short* __restrict__ ol) {
  __shared__ unsigned int hist[4][128];     // 256 buckets packed 2x u16
  __shared__ unsigned short lidx[4][224];
  __shared__ float lw[4][224];

  int t = threadIdx.x;
  int w = t >> 6, lane = t & 63;
  int rs = blockIdx.x * 4 + w;              // 0..16383 within slice
  int h8 = rs >> 11;
  int i = rs & 2047;
  int h = h0 + h8;
  const float* srow = scb + (size_t)rs * S_;
  size_t grow = ((size_t)(b * NH_ + h)) * S_ + i;
  unsigned int fw = pf[grow * (S_ / 32) + lane];

  int hi = i - WINDOW_;
  int C = hi - SINKS_ + 1;
  int mode = (C <= 0) ? 0 : (C <= KTOP_ ? 1 : 2);
  unsigned int T16 = 0; int neq = 0;

  if (mode == 2) {
    int cmax = hi >> 6;
    unsigned int need = KTOP_;
    unsigned int d0_, d1_;
    // ---- pass 0: top 8 bits ----
    hist[w][lane] = 0; hist[w][lane + 64] = 0;
    for (int c = 0; c <= cmax; ++c) {
      int j = c * 64 + lane;
      float s = srow[j];
      bool cand = (j >= SINKS_) && (j <= hi);
      if (cand) {
        unsigned int bkt = mono(s) >> 24;
        atomicAdd(&hist[w][bkt >> 1], 1u << ((bkt & 1u) * 16));
      }
    }
    {
      unsigned int w0 = hist[w][lane * 2], w1 = hist[w][lane * 2 + 1];
      unsigned int s0 = (w0 & 0xffffu) + (w0 >> 16) + (w1 & 0xffffu) + (w1 >> 16);
      unsigned int suf = s0;
#pragma unroll
      for (int off = 1; off < 64; off <<= 1) {
        unsigned int vv = __shfl_down(suf, off);
        if (lane + off < 64) suf += vv;
      }
      unsigned int sufn = __shfl_down(suf, 1);
      if (lane == 63) sufn = 0;
      bool pl = (suf >= need) && (sufn < need);
      unsigned long long bal = __ballot(pl);
      int gg = __ffsll(bal) - 1;
      unsigned int basec = __shfl(sufn, gg);
      unsigned int cum = basec; int dstar = 4 * gg;
#pragma unroll
      for (int dd = 3; dd >= 0; --dd) {
        int d = 4 * gg + dd;
        unsigned int hd = (hist[w][d >> 1] >> ((d & 1) * 16)) & 0xffffu;
        cum += hd;
        if (cum >= need) { dstar = d; break; }
      }
      unsigned int hstar = (hist[w][dstar >> 1] >> ((dstar & 1) * 16)) & 0xffffu;
      need -= (cum - hstar);
      d0_ = (unsigned int)dstar;
    }
    // ---- pass 1: bits 23:16 among top-8 == d0_ ----
    hist[w][lane] = 0; hist[w][lane + 64] = 0;
    for (int c = 0; c <= cmax; ++c) {
      int j = c * 64 + lane;
      float s = srow[j];
      bool cand = (j >= SINKS_) && (j <= hi);
      if (cand) {
        unsigned int key = mono(s);
        if ((key >> 24) == d0_) {
          unsigned int bkt = (key >> 16) & 255u;
          atomicAdd(&hist[w][bkt >> 1], 1u << ((bkt & 1u) * 16));
        }
      }
    }
    {
      unsigned int w0 = hist[w][lane * 2], w1 = hist[w][lane * 2 + 1];
      unsigned int s0 = (w0 & 0xffffu) + (w0 >> 16) + (w1 & 0xffffu) + (w1 >> 16);
      unsigned int suf = s0;
#pragma unroll
      for (int off = 1; off < 64; off <<= 1) {
        unsigned int vv = __shfl_down(suf, off);
        if (lane + off < 64) suf += vv;
      }
      unsigned int sufn = __shfl_down(suf, 1);
      if (lane == 63) sufn = 0;
      bool pl = (suf >= need) && (sufn < need);
      unsigned long long bal = __ballot(pl);
      int gg = __ffsll(bal) - 1;
      unsigned int basec = __shfl(sufn, gg);
      unsigned int cum = basec; int dstar = 4 * gg;
#pragma unroll
      for (int dd = 3; dd >= 0; --dd) {
        int d = 4 * gg + dd;
        unsigned int hd = (hist[w][d >> 1] >> ((d & 1) * 16)) & 0xffffu;
        cum += hd;
        if (cum >= need) { dstar = d; break; }
      }
      unsigned int hstar = (hist[w][dstar >> 1] >> ((dstar & 1) * 16)) & 0xffffu;
      need -= (cum - hstar);
      d1_ = (unsigned int)dstar;
    }
    T16 = (d0_ << 8) | d1_;
    neq = (int)need;
  }

  // ---- marking: base | topk(>T16, ties ascending), forget on topk; compact + vmax ----
  float vmax = -3.4e38f;
  int neq_run = neq;
  int cnt = 0;
  int nch = i >> 6;
  for (int c = 0; c <= nch; ++c) {
    int j = c * 64 + lane;
    unsigned int wv = __shfl(fw, c * 2 + (lane >> 5));  // uniform-active shfl
    bool fbit = (wv >> (j & 31)) & 1;
    bool valid = j <= i;
    float s = srow[j];
    bool isbase = valid && ((j < SINKS_) || ((i - j) < WINDOW_));
    bool iscand = valid && !isbase;
    bool sel = false, iseq = false;
    if (iscand) {
      if (mode == 1) sel = true;
      else if (mode == 2) {
        unsigned int k16 = mono(s) >> 16;
        sel = k16 > T16;
        iseq = (k16 == T16);
      }
    }
    unsigned long long em = __ballot(iseq);
    if (iseq) {
      int rk = __popcll(em & ((1ull << lane) - 1ull));
      if (rk < neq_run) sel = true;
    }
    int taken = __popcll(em);
    neq_run -= (taken < neq_run) ? taken : neq_run;
    if (sel && fbit) sel = false;
    bool allowed = isbase || sel;
    if (allowed) vmax = fmaxf(vmax, s);
    unsigned long long am = __ballot(allowed);
    if (allowed) {
      int pos = cnt + __popcll(am & ((1ull << lane) - 1ull));
      lidx[w][pos] = (unsigned short)j;
      lw[w][pos] = s;
    }
    cnt += __popcll(am);
  }
#pragma unroll
  for (int off = 32; off >= 1; off >>= 1) vmax = fmaxf(vmax, __shfl_xor(vmax, off));

  // ---- weights ----
  float sum = 0.f;
  for (int p = lane; p < cnt; p += 64) {
    float wgt = __expf(lw[w][p] - vmax);
    lw[w][p] = wgt;
    sum += wgt;
  }
#pragma unroll
  for (int off = 32; off >= 1; off >>= 1) sum += __shfl_xor(sum, off);
  float inv = 1.0f / sum;

  // ---- PV: lane q<32 handles dims 4q..4q+3; wave halves split the list ----
  int half = lane >> 5;
  int q = lane & 31;
  int d0 = q * 4;
  int pmid = (cnt + 1) >> 1;
  int p0 = half ? pmid : 0;
  int p1 = half ? cnt : pmid;
  size_t vbase = ((size_t)b * S_) * HD_ + h * DH_ + d0;

  float a0 = 0.f, a1 = 0.f, a2 = 0.f, a3 = 0.f;
  int p = p0;
  for (; p + 4 <= p1; p += 4) {
    int ja = lidx[w][p],     jb = lidx[w][p + 1];
    int jc = lidx[w][p + 2], jd = lidx[w][p + 3];
    float wa = lw[w][p], wb = lw[w][p + 1], wc = lw[w][p + 2], wd = lw[w][p + 3];
    uint2 va = *(const uint2*)(vbf + vbase + (size_t)ja * HD_);
    uint2 vb = *(const uint2*)(vbf + vbase + (size_t)jb * HD_);
    uint2 vc = *(const uint2*)(vbf + vbase + (size_t)jc * HD_);
    uint2 vd = *(const uint2*)(vbf + vbase + (size_t)jd * HD_);
    a0 += wa * bfLO(va.x) + wb * bfLO(vb.x) + wc * bfLO(vc.x) + wd * bfLO(vd.x);
    a1 += wa * bfHI(va.x) + wb * bfHI(vb.x) + wc * bfHI(vc.x) + wd * bfHI(vd.x);
    a2 += wa * bfLO(va.y) + wb * bfLO(vb.y) + wc * bfLO(vc.y) + wd * bfLO(vd.y);
    a3 += wa * bfHI(va.y) + wb * bfHI(vb.y) + wc * bfHI(vc.y) + wd * bfHI(vd.y);
  }
  for (; p < p1; ++p) {
    int jj = lidx[w][p];
    float wj = lw[w][p];
    uint2 vj = *(const uint2*)(vbf + vbase + (size_t)jj * HD_);
    a0 += wj * bfLO(vj.x); a1 += wj * bfHI(vj.x);
    a2 += wj * bfLO(vj.y); a3 += wj * bfHI(vj.y);
  }
  a0 += __shfl_xor(a0, 32);
  a1 += __shfl_xor(a1, 32);
  a2 += __shfl_xor(a2, 32);
  a3 += __shfl_xor(a3, 32);
  if (half == 0) {
    float v0 = a0 * inv, v1 = a1 * inv, v2 = a2 * inv, v3 = a3 * inv;
    ushort4 ho, lo4;
    ho.x = f2bf(v0); lo4.x = f2bf(v0 - bf2f(ho.x));
    ho.y = f2bf(v1); lo4.y = f2bf(v1 - bf2f(ho.y));
    ho.z = f2bf(v2); lo4.z = f2bf(v2 - bf2f(ho.z));
    ho.w = f2bf(v3); lo4.w = f2bf(v3 - bf2f(ho.w));
    size_t oidx = ((size_t)(b * S_ + i)) * HD_ + h * DH_ + d0;
    *(ushort4*)(oh + oidx) = ho;
    *(ushort4*)(ol + oidx) = lo4;
  }
}

extern "C" void kernel_launch(void* const* d_in, const int* in_sizes, int n_in,
                              void* d_out, int out_size, void* d_ws, size_t ws_size,
                              hipStream_t stream) {
  (void)in_sizes; (void)n_in; (void)out_size; (void)ws_size;
  const float* x  = (const float*)d_in[0];
  const float* Wq = (const float*)d_in[1];
  const float* Wc = (const float*)d_in[2];
  const float* Wk = (const float*)d_in[3];
  const float* Wv = (const float*)d_in[4];
  const float* Wo = (const float*)d_in[5];
  const int* forget = (const int*)d_in[6];  // bool widened to int32 (verified r3)

  char* ws = (char*)d_ws;
  size_t off = 0;
  auto alloc = [&](size_t bytes) { char* p = ws + off; off += (bytes + 255) & ~(size_t)255; return p; };

  unsigned short* x_hi = (unsigned short*)alloc((size_t)4096 * 2048 * 2);  // reused as o_hi
  unsigned short* x_lo = (unsigned short*)alloc((size_t)4096 * 2048 * 2);  // reused as o_lo
  unsigned short* WqTh = (unsigned short*)alloc((size_t)2048 * 2048 * 2);
  unsigned short* WqTl = (unsigned short*)alloc((size_t)2048 * 2048 * 2);
  unsigned short* WcTh = (unsigned short*)alloc((size_t)512 * 2048 * 2);
  unsigned short* WcTl = (unsigned short*)alloc((size_t)512 * 2048 * 2);
  unsigned short* WkTh = (unsigned short*)alloc((size_t)2048 * 512 * 2);
  unsigned short* WkTl = (unsigned short*)alloc((size_t)2048 * 512 * 2);
  unsigned short* WvTh = (unsigned short*)alloc((size_t)2048 * 512 * 2);
  unsigned short* WvTl = (unsigned short*)alloc((size_t)2048 * 512 * 2);
  unsigned short* WoTh = (unsigned short*)alloc((size_t)2048 * 2048 * 2);
  unsigned short* WoTl = (unsigned short*)alloc((size_t)2048 * 2048 * 2);
  unsigned short* q_hi = (unsigned short*)alloc((size_t)4096 * 2048 * 2);
  unsigned short* q_lo = (unsigned short*)alloc((size_t)4096 * 2048 * 2);
  unsigned short* c_hi = (unsigned short*)alloc((size_t)4096 * 512 * 2);
  unsigned short* c_lo = (unsigned short*)alloc((size_t)4096 * 512 * 2);
  unsigned short* k_hi = (unsigned short*)alloc((size_t)4096 * 2048 * 2);
  unsigned short* k_lo = (unsigned short*)alloc((size_t)4096 * 2048 * 2);
  unsigned short* v_bf = (unsigned short*)alloc((size_t)4096 * 2048 * 2);
  unsigned int*  fpack = (unsigned int*)alloc((size_t)(134217728 / 8));
  float*          scb  = (float*)alloc((size_t)16384 * 2048 * 4);   // 128 MB slice buffer

  unsigned short* o_hi = x_hi;
  unsigned short* o_lo = x_lo;

  pack_forget<<<8192, 256, 0, stream>>>(forget, fpack, 134217728LL);

  split_f32<<<2048, 256, 0, stream>>>(x, x_hi, x_lo, 4096 * 2048);
  transpose_split<<<dim3(64, 64), 256, 0, stream>>>(Wq, WqTh, WqTl, 2048, 2048);
  transpose_split<<<dim3(16, 64), 256, 0, stream>>>(Wc, WcTh, WcTl, 2048, 512);
  transpose_split<<<dim3(64, 16), 256, 0, stream>>>(Wk, WkTh, WkTl, 512, 2048);
  transpose_split<<<dim3(64, 16), 256, 0, stream>>>(Wv, WvTh, WvTl, 512, 2048);
  transpose_split<<<dim3(64, 64), 256, 0, stream>>>(Wo, WoTh, WoTl, 2048, 2048);

  gemm_split<<<dim3(32, 4),  256, 0, stream>>>(x_hi, x_lo, WcTh, WcTl, nullptr, c_hi, c_lo, 4096, 512, 2048);
  gemm_split<<<dim3(32, 16), 256, 0, stream>>>(x_hi, x_lo, WqTh, WqTl, nullptr, q_hi, q_lo, 4096, 2048, 2048);
  gemm_split<<<dim3(32, 16), 256, 0, stream>>>(c_hi, c_lo, WkTh, WkTl, nullptr, k_hi, k_lo, 4096, 2048, 512);
  gemm_split<<<dim3(32, 16), 256, 0, stream>>>(c_hi, c_lo, WvTh, WvTl, nullptr, v_bf, nullptr, 4096, 2048, 512);

  for (int s = 0; s < 4; ++s) {
    int b = s >> 1;
    int h0 = (s & 1) * 8;
    attn_scores<<<dim3(128, 8), 256, 0, stream>>>(q_hi, q_lo, k_hi, k_lo, b, h0, scb);
    attn_select2<<<4096, 256, 0, stream>>>(scb, v_bf, fpack, b, h0, o_hi, o_lo);
  }

  gemm_split<<<dim3(32, 16), 256, 0, stream>>>(o_hi, o_lo, WoTh, WoTl, (float*)d_out, nullptr, nullptr, 4096, 2048, 2048);
}